// Round 14
// baseline (26.624 us; speedup 1.0000x reference)
//
#include <hip/hip_runtime.h>
#include <stdint.h>

#define K_DIM 4096
#define KW 1024          // packed words per m-row
#define M_DIM 11008
#define B_DIM 16
#define GROUP_ROWS 2752  // M / 4 groups
#define QTR_W 256
#define NTILES 688       // M / 16

typedef int v4i __attribute__((ext_vector_type(4)));

// spread low byte p (4x 2-bit fields) into 4 bytes: {p&3,(p>>2)&3,(p>>4)&3,(p>>6)&3}
__device__ __forceinline__ int spread2(int p) {
    int t = p | (p << 12);
    return (t & 0x00030003) | (((t >> 2) & 0x00030003) << 8);
}

// ---------------- kernel 1: per-row activation quantization (R13 verbatim) ----------------
__global__ __launch_bounds__(256) void quant_k(const float* __restrict__ in,
                                               int* __restrict__ qg,
                                               int* __restrict__ sumq_part,
                                               float* __restrict__ invs) {
    const int g = blockIdx.x, b = g >> 2, qt = g & 3;
    const int t = threadIdx.x, lane = t & 63, wid = t >> 6;

    const float4* row = (const float4*)(in + (size_t)b * K_DIM);
    float4 v[4];
#pragma unroll
    for (int i = 0; i < 4; ++i) v[i] = row[t + i * 256];

    float mx = 0.f;
#pragma unroll
    for (int i = 0; i < 4; ++i) {
        mx = fmaxf(mx, fabsf(v[i].x)); mx = fmaxf(mx, fabsf(v[i].y));
        mx = fmaxf(mx, fabsf(v[i].z)); mx = fmaxf(mx, fabsf(v[i].w));
    }
#pragma unroll
    for (int s = 1; s < 64; s <<= 1) mx = fmaxf(mx, __shfl_xor(mx, s, 64));

    __shared__ float wmax[4];
    __shared__ int wsum[4];
    if (lane == 0) wmax[wid] = mx;
    __syncthreads();
    const float bm = fmaxf(fmaxf(wmax[0], wmax[1]), fmaxf(wmax[2], wmax[3]));
    const float sc = 127.f / fmaxf(bm, 1e-5f);

    const float4 mine = v[qt];  // thread t quantizes word qt*256 + t
    float xs[4] = {mine.x, mine.y, mine.z, mine.w};
    int w = 0, ss = 0;
#pragma unroll
    for (int j = 0; j < 4; ++j) {
        int q = (int)rintf(xs[j] * sc);   // round-half-even, matches jnp.round
        q = q > 127 ? 127 : (q < -128 ? -128 : q);
        ss += q;
        w |= (q & 255) << (8 * j);
    }
    qg[b * KW + qt * QTR_W + t] = w;

#pragma unroll
    for (int s = 1; s < 64; s <<= 1) ss += __shfl_xor(ss, s, 64);
    if (lane == 0) wsum[wid] = ss;
    __syncthreads();
    if (t == 0) {
        sumq_part[b * 4 + qt] = wsum[0] + wsum[1] + wsum[2] + wsum[3];
        if (qt == 0) invs[b] = fmaxf(bm, 1e-5f) / 127.f;
    }
}

// ---------------- kernel 2: fine-grained streaming ternary GEMM ----------------
// 2752 blocks x 64 thr (ONE wave each): block = (tile = bid>>2, K-quarter = bid&3).
// 10.75 waves/CU (LDS 16 KB -> 10 blocks/CU), ~7% tail vs R8's 25%. Per wave:
// 16 q-frag loads, 16 row-loads (each ONE contiguous 1 KB instruction, rolling
// 8-reg buffer), stage once to private LDS (XOR-swizzled granules), ONE lgkm
// wait, straight-line 16 MFMA steps, 1 KB partial store. No barriers, no NT,
// one LDS round-trip per wave. Latency hidden by 10-wave interleave per CU.
__global__ __launch_bounds__(64, 4) void gemm_k(const int* __restrict__ wp,
                                                const int* __restrict__ qg,
                                                int* __restrict__ part) {
    __shared__ int lds[16 * 256];  // 16 KB: [row][word], 16B granules XOR-swizzled
    const int lane = threadIdx.x;
    const int bid = blockIdx.x;
    const int tile = bid >> 2, qt = bid & 3;
    const int m0 = tile * 16;
    const int lrow = lane & 15;   // b for A-frag, m for B-frag
    const int lgrp = lane >> 4;   // k-granule phase within a 64-k MFMA step

    // q fragments first (oldest in vmcnt queue; L2-hot)
    v4i qr[16];
#pragma unroll
    for (int s = 0; s < 16; ++s)
        qr[s] = *(const v4i*)(qg + lrow * KW + qt * QTR_W + s * 16 + lgrp * 4);

    const int* wb = wp + (size_t)m0 * KW + qt * QTR_W;

    // rows 0..7: contiguous 1 KB per instruction, 8 in flight
    v4i w8[8];
#pragma unroll
    for (int r = 0; r < 8; ++r)
        w8[r] = *(const v4i*)(wb + (size_t)r * KW + lane * 4);
    // stage rows 0..7 (compiler inserts progressive vmcnt waits)
#pragma unroll
    for (int r = 0; r < 8; ++r)
        *(v4i*)(lds + r * 256 + (lane ^ (r & 7)) * 4) = w8[r];
    // rows 8..15 into the same regs (compiler orders vs pending ds_writes)
#pragma unroll
    for (int r = 0; r < 8; ++r)
        w8[r] = *(const v4i*)(wb + (size_t)(8 + r) * KW + lane * 4);
#pragma unroll
    for (int r = 0; r < 8; ++r)
        *(v4i*)(lds + (8 + r) * 256 + (lane ^ (r & 7)) * 4) = w8[r];

    asm volatile("s_waitcnt lgkmcnt(0)" ::: "memory");  // all 16 rows staged (own wave)

    // 16 straight-line MFMA steps (k = qt*1024 + s*64)
    v4i acc = {0, 0, 0, 0};
#pragma unroll
    for (int s = 0; s < 16; ++s) {
        const int g = s * 4 + lgrp;
        v4i wv = *(const v4i*)(lds + lrow * 256 + (g ^ (lrow & 7)) * 4);
        v4i bb;
        bb[0] = spread2(wv[0]); bb[1] = spread2(wv[1]);
        bb[2] = spread2(wv[2]); bb[3] = spread2(wv[3]);
        acc = __builtin_amdgcn_mfma_i32_16x16x64_i8(qr[s], bb, acc, 0, 0, 0);
    }

    // partial store: contiguous 1 KB. part[bid*256 + lane*4 + reg]
    // holds D[b=(lane>>4)*4+reg][m=lane&15] for this K-quarter.
    *(v4i*)(part + bid * 256 + lane * 4) = acc;
}

// ---------------- kernel 3: combine 4 K-quarter partials + scale ----------------
__global__ __launch_bounds__(256) void finalize_k(const int* __restrict__ part,
                                                  const int* __restrict__ sumq_part,
                                                  const float* __restrict__ invs,
                                                  const float* __restrict__ wscale,
                                                  float* __restrict__ out) {
    const int tile = blockIdx.x, t = threadIdx.x;
    const int b = t >> 4, m = t & 15;
    const int sl = ((b >> 2) << 4) | m;   // D layout: col=lane&15, row=(lane>>4)*4+reg
    const int rg = b & 3;
    const int base = tile * 4 * 256 + sl * 4 + rg;
    const int sum = part[base] + part[base + 256] + part[base + 512] + part[base + 768];
    const int sq = sumq_part[b * 4 + 0] + sumq_part[b * 4 + 1] +
                   sumq_part[b * 4 + 2] + sumq_part[b * 4 + 3];
    const float val = (float)(sum - sq) * invs[b] * wscale[(tile * 16) / GROUP_ROWS];
    out[(size_t)b * M_DIM + tile * 16 + m] = val;
}

extern "C" void kernel_launch(void* const* d_in, const int* in_sizes, int n_in,
                              void* d_out, int out_size, void* d_ws, size_t ws_size,
                              hipStream_t stream) {
    const float* inp    = (const float*)d_in[0];
    const int*   wp     = (const int*)d_in[1];
    const float* wscale = (const float*)d_in[2];
    float* out = (float*)d_out;

    int*   qg   = (int*)d_ws;                  // 16384 words = 64 KB
    int*   sqp  = qg + B_DIM * KW;             // 64 ints
    float* invs = (float*)(sqp + B_DIM * 4);   // 16 floats
    int*   part = (int*)(invs + B_DIM);        // 2752*256 ints = 2.82 MB

    quant_k<<<dim3(B_DIM * 4), dim3(256), 0, stream>>>(inp, qg, sqp, invs);
    gemm_k<<<dim3(NTILES * 4), dim3(64), 0, stream>>>(wp, qg, part);
    finalize_k<<<dim3(NTILES), dim3(256), 0, stream>>>(part, sqp, invs, wscale, out);
}